// Round 5
// baseline (159.244 us; speedup 1.0000x reference)
//
#include <hip/hip_runtime.h>

#define BB 4
#define NN 16384
#define MM 8192      // N/2
#define FD 64
#define CHUNK 512    // candidates staged per LDS tile
#define QPT 4        // queries per thread (register-blocked)
#define TPB 256      // threads per block
#define QPB (TPB * QPT)   // 1024 queries per block

// d_out float offsets (outputs concatenated flat in return order)
#define OUT0 0              // valid_pc   (4,8192,3)  = 98304
#define OUT1 98304          // valid_feats(4,8192,64) = 2097152
#define OUT2 2195456        // n_idx      (4,8192)    = 32768
#define OUT3 2228224        // rnds       (1,16384)   = 16384

struct Partial { float m1, m2; int i1, i2; };  // 16B

// Reference fp32 chain (verified absmax=0): rounded squares, sequential adds.
__device__ __forceinline__ float sumsq3_rn(float x, float y, float z) {
  return __fadd_rn(__fadd_rn(__fmul_rn(x, x), __fmul_rn(y, y)), __fmul_rn(z, z));
}
// gemm K-loop chain: acc = fma(z, fma(y, rn(x)))
__device__ __forceinline__ float dot3_gemm(float ax, float ay, float az,
                                           float bx, float by, float bz) {
  return __fmaf_rn(az, bz, __fmaf_rn(ay, by, __fmul_rn(ax, bx)));
}

__global__ __launch_bounds__(256) void gather_kernel(
    const float* __restrict__ pc, const float* __restrict__ feats,
    const int* __restrict__ perm, float* __restrict__ out) {
  int idx = blockIdx.x * 256 + threadIdx.x;
  const int F4_TOT = BB * MM * FD / 4;   // 524288 float4 of feats
  const int PTS    = BB * MM;            // 32768 valid points (pc)
  if (idx < F4_TOT) {
    int f4 = idx & 15;                   // float4 within row
    int r  = (idx >> 4) & (MM - 1);
    int b  = idx >> 17;                  // / (MM*16)
    int vi = perm[r];
    const float4* src = (const float4*)(feats + ((b * NN + vi) << 6));
    float4* dst = (float4*)(out + OUT1) + idx;
    *dst = src[f4];
  } else if (idx < F4_TOT + PTS) {
    int k = idx - F4_TOT;
    int r = k & (MM - 1);
    int b = k >> 13;
    int vi = perm[r];
    const float* src = pc + (b * NN + vi) * 3;
    float* dst = out + OUT0 + k * 3;
    dst[0] = src[0]; dst[1] = src[1]; dst[2] = src[2];
  } else if (idx < F4_TOT + PTS + NN) {
    int k = idx - F4_TOT - PTS;
    out[OUT3 + k] = (float)perm[k];
  }
}

// Each block: QPB queries (4/thread in registers) x (MM/nchunk) candidates.
// nchunk>1: per-chunk top-2 partials to `part`; nchunk==1: final index to out.
__global__ __launch_bounds__(256) void knn_kernel(
    const float* __restrict__ pc, const int* __restrict__ perm,
    Partial* __restrict__ part, float* __restrict__ out, int nchunk) {
  #pragma clang fp contract(off)
  int blk = blockIdx.x;
  int c  = blk % nchunk;          // chunk id
  int qb = blk / nchunk;          // query-block id
  int q0 = qb * QPB + threadIdx.x;   // first of QPT strided queries
  int b  = q0 >> 13;              // QPB divides MM -> whole block same batch

  float qx[QPT], qy[QPT], qz[QPT], q2[QPT];
  float m1[QPT], m2[QPT];
  int   i1[QPT], i2[QPT];
  #pragma unroll
  for (int s = 0; s < QPT; ++s) {
    int q = q0 + s * TPB;
    int j = q & (MM - 1);
    int qi = perm[MM + j];
    const float* qp = pc + (b * NN + qi) * 3;
    qx[s] = qp[0]; qy[s] = qp[1]; qz[s] = qp[2];
    q2[s] = sumsq3_rn(qx[s], qy[s], qz[s]);
    m1[s] = 3.4e38f; m2[s] = 3.4e38f; i1[s] = 0; i2[s] = 0;
  }

  __shared__ float4 tile[CHUNK];   // (x, y, z, p2)  8 KB

  int span = MM / nchunk;
  int begin = c * span, end = begin + span;

  for (int t0 = begin; t0 < end; t0 += CHUNK) {
    __syncthreads();
    for (int k = threadIdx.x; k < CHUNK; k += TPB) {
      int vi = perm[t0 + k];
      const float* pp = pc + (b * NN + vi) * 3;
      float px = pp[0], py = pp[1], pz = pp[2];
      tile[k] = make_float4(px, py, pz, sumsq3_rn(px, py, pz));
    }
    __syncthreads();
    #pragma unroll 2
    for (int k = 0; k < CHUNK; ++k) {
      float4 t = tile[k];
      #pragma unroll
      for (int s = 0; s < QPT; ++s) {
        float cross = dot3_gemm(qx[s], qy[s], qz[s], t.x, t.y, t.z);
        float d2 = __fadd_rn(__fsub_rn(q2[s], __fmul_rn(2.0f, cross)), t.w);
        if (d2 < m2[s]) {
          if (d2 < m1[s]) { m2[s] = m1[s]; i2[s] = i1[s]; m1[s] = d2; i1[s] = t0 + k; }
          else            { m2[s] = d2; i2[s] = t0 + k; }
        }
      }
    }
  }

  #pragma unroll
  for (int s = 0; s < QPT; ++s) {
    int q = q0 + s * TPB;
    if (part != nullptr) {
      Partial pr; pr.m1 = m1[s]; pr.m2 = m2[s]; pr.i1 = i1[s]; pr.i2 = i2[s];
      part[q * nchunk + c] = pr;
    } else {
      out[OUT2 + q] = (float)i2[s];
    }
  }
}

__global__ __launch_bounds__(256) void knn_merge_kernel(
    const Partial* __restrict__ part, float* __restrict__ out, int nchunk) {
  int q = blockIdx.x * 256 + threadIdx.x;   // 0..B*M-1
  float m1 = 3.4e38f, m2 = 3.4e38f;
  int i1 = 0, i2 = 0;
  for (int c = 0; c < nchunk; ++c) {
    Partial p = part[q * nchunk + c];
    // ascending chunk order = ascending candidate-index ranges, so strict <
    // preserves top_k's stable lowest-index-first tie semantics.
    if (p.m1 < m1)      { m2 = m1; i2 = i1; m1 = p.m1; i1 = p.i1; }
    else if (p.m1 < m2) { m2 = p.m1; i2 = p.i1; }
    if (p.m2 < m1)      { m2 = m1; i2 = i1; m1 = p.m2; i1 = p.i2; }
    else if (p.m2 < m2) { m2 = p.m2; i2 = p.i2; }
  }
  out[OUT2 + q] = (float)i2;
}

extern "C" void kernel_launch(void* const* d_in, const int* in_sizes, int n_in,
                              void* d_out, int out_size, void* d_ws, size_t ws_size,
                              hipStream_t stream) {
  const float* pc    = (const float*)d_in[0];
  const float* feats = (const float*)d_in[1];
  const int*   perm  = (const int*)d_in[2];
  float* out = (float*)d_out;

  // Gather domains: 524288 float4 + 32768 pts + 16384 rnds = 573440 -> 2240 blocks
  gather_kernel<<<2240, 256, 0, stream>>>(pc, feats, perm, out);

  // Largest chunk split whose partials fit in d_ws (16 -> 512 blocks = 2/CU).
  int nchunk = 1;
  if      (ws_size >= (size_t)BB * MM * 16 * sizeof(Partial)) nchunk = 16;  // 8.4 MB
  else if (ws_size >= (size_t)BB * MM * 8  * sizeof(Partial)) nchunk = 8;   // 4.2 MB
  else if (ws_size >= (size_t)BB * MM * 4  * sizeof(Partial)) nchunk = 4;
  else if (ws_size >= (size_t)BB * MM * 2  * sizeof(Partial)) nchunk = 2;

  int qblocks = BB * MM / QPB;   // 32
  if (nchunk > 1) {
    Partial* part = (Partial*)d_ws;
    knn_kernel<<<qblocks * nchunk, TPB, 0, stream>>>(pc, perm, part, out, nchunk);
    knn_merge_kernel<<<BB * MM / 256, 256, 0, stream>>>(part, out, nchunk);
  } else {
    knn_kernel<<<qblocks, TPB, 0, stream>>>(pc, perm, nullptr, out, 1);
  }
}

// Round 6
// 96.874 us; speedup vs baseline: 1.6438x; 1.6438x over previous
//
#include <hip/hip_runtime.h>

#define BB 4
#define NN 16384
#define MM 8192      // N/2
#define FD 64
#define CHUNK 256    // candidates staged per LDS tile (1 per thread)
#define QPT 2        // queries per thread (register-blocked)
#define TPB 256      // threads per block
#define QPB (TPB * QPT)   // 512 queries per block

// d_out float offsets (outputs concatenated flat in return order)
#define OUT0 0              // valid_pc   (4,8192,3)  = 98304
#define OUT1 98304          // valid_feats(4,8192,64) = 2097152
#define OUT2 2195456        // n_idx      (4,8192)    = 32768
#define OUT3 2228224        // rnds       (1,16384)   = 16384

struct Partial { float m1, m2; int i1, i2; };  // 16B

// Reference fp32 chain (verified absmax=0): rounded squares, sequential adds.
__device__ __forceinline__ float sumsq3_rn(float x, float y, float z) {
  return __fadd_rn(__fadd_rn(__fmul_rn(x, x), __fmul_rn(y, y)), __fmul_rn(z, z));
}
// gemm K-loop chain: acc = fma(z, fma(y, rn(x)))
__device__ __forceinline__ float dot3_gemm(float ax, float ay, float az,
                                           float bx, float by, float bz) {
  return __fmaf_rn(az, bz, __fmaf_rn(ay, by, __fmul_rn(ax, bx)));
}

__global__ __launch_bounds__(256) void gather_kernel(
    const float* __restrict__ pc, const float* __restrict__ feats,
    const int* __restrict__ perm, float* __restrict__ out) {
  int idx = blockIdx.x * 256 + threadIdx.x;
  const int F4_TOT = BB * MM * FD / 4;   // 524288 float4 of feats
  const int PTS    = BB * MM;            // 32768 valid points (pc)
  if (idx < F4_TOT) {
    int f4 = idx & 15;                   // float4 within row
    int r  = (idx >> 4) & (MM - 1);
    int b  = idx >> 17;                  // / (MM*16)
    int vi = perm[r];
    const float4* src = (const float4*)(feats + ((b * NN + vi) << 6));
    float4* dst = (float4*)(out + OUT1) + idx;
    *dst = src[f4];
  } else if (idx < F4_TOT + PTS) {
    int k = idx - F4_TOT;
    int r = k & (MM - 1);
    int b = k >> 13;
    int vi = perm[r];
    const float* src = pc + (b * NN + vi) * 3;
    float* dst = out + OUT0 + k * 3;
    dst[0] = src[0]; dst[1] = src[1]; dst[2] = src[2];
  } else if (idx < F4_TOT + PTS + NN) {
    int k = idx - F4_TOT - PTS;
    out[OUT3 + k] = (float)perm[k];
  }
}

// Each block: QPB queries (QPT/thread in registers) x (MM/nchunk) candidates.
// nchunk>1: per-chunk top-2 partials to `part`; nchunk==1: final index to out.
__global__ __launch_bounds__(256) void knn_kernel(
    const float* __restrict__ pc, const int* __restrict__ perm,
    Partial* __restrict__ part, float* __restrict__ out, int nchunk) {
  #pragma clang fp contract(off)
  int blk = blockIdx.x;
  int c  = blk % nchunk;          // chunk id
  int qb = blk / nchunk;          // query-block id
  int q0 = qb * QPB + threadIdx.x;   // first of QPT strided queries
  int b  = q0 >> 13;              // QPB divides MM -> whole block same batch

  float qx[QPT], qy[QPT], qz[QPT], q2[QPT], m1[QPT], m2[QPT];
  int   i1[QPT], i2[QPT];
  #pragma unroll
  for (int s = 0; s < QPT; ++s) {
    int q = q0 + s * TPB;
    int j = q & (MM - 1);
    int qi = perm[MM + j];
    const float* qp = pc + (b * NN + qi) * 3;
    qx[s] = qp[0]; qy[s] = qp[1]; qz[s] = qp[2];
    q2[s] = sumsq3_rn(qx[s], qy[s], qz[s]);
    m1[s] = 3.4e38f; m2[s] = 3.4e38f; i1[s] = 0; i2[s] = 0;
  }

  __shared__ float4 tile[CHUNK];   // (x, y, z, p2)  4 KB

  int span = MM / nchunk;
  int begin = c * span, end = begin + span;

  for (int t0 = begin; t0 < end; t0 += CHUNK) {
    __syncthreads();
    {
      int k = threadIdx.x;                 // CHUNK == TPB: one each
      int vi = perm[t0 + k];
      const float* pp = pc + (b * NN + vi) * 3;
      float px = pp[0], py = pp[1], pz = pp[2];
      tile[k] = make_float4(px, py, pz, sumsq3_rn(px, py, pz));
    }
    __syncthreads();
    #pragma unroll 4
    for (int k = 0; k < CHUNK; ++k) {
      float4 t = tile[k];
      int idx = t0 + k;
      #pragma unroll
      for (int s = 0; s < QPT; ++s) {
        float cross = dot3_gemm(qx[s], qy[s], qz[s], t.x, t.y, t.z);
        float d2 = __fadd_rn(__fsub_rn(q2[s], __fmul_rn(2.0f, cross)), t.w);
        // branchless stable top-2 (strict <, ascending idx order)
        bool lt1 = d2 < m1[s];
        bool lt2 = d2 < m2[s];
        m2[s] = lt1 ? m1[s] : (lt2 ? d2 : m2[s]);
        i2[s] = lt1 ? i1[s] : (lt2 ? idx : i2[s]);
        m1[s] = lt1 ? d2 : m1[s];
        i1[s] = lt1 ? idx : i1[s];
      }
    }
  }

  #pragma unroll
  for (int s = 0; s < QPT; ++s) {
    int q = q0 + s * TPB;
    if (part != nullptr) {
      Partial pr; pr.m1 = m1[s]; pr.m2 = m2[s]; pr.i1 = i1[s]; pr.i2 = i2[s];
      part[q * nchunk + c] = pr;
    } else {
      out[OUT2 + q] = (float)i2[s];
    }
  }
}

__global__ __launch_bounds__(256) void knn_merge_kernel(
    const Partial* __restrict__ part, float* __restrict__ out, int nchunk) {
  int q = blockIdx.x * 256 + threadIdx.x;   // 0..B*M-1
  float m1 = 3.4e38f, m2 = 3.4e38f;
  int i1 = 0, i2 = 0;
  for (int c = 0; c < nchunk; ++c) {
    Partial p = part[q * nchunk + c];
    // ascending chunk order = ascending candidate-index ranges, so strict <
    // preserves top_k's stable lowest-index-first tie semantics.
    if (p.m1 < m1)      { m2 = m1; i2 = i1; m1 = p.m1; i1 = p.i1; }
    else if (p.m1 < m2) { m2 = p.m1; i2 = p.i1; }
    if (p.m2 < m1)      { m2 = m1; i2 = i1; m1 = p.m2; i1 = p.i2; }
    else if (p.m2 < m2) { m2 = p.m2; i2 = p.i2; }
  }
  out[OUT2 + q] = (float)i2;
}

extern "C" void kernel_launch(void* const* d_in, const int* in_sizes, int n_in,
                              void* d_out, int out_size, void* d_ws, size_t ws_size,
                              hipStream_t stream) {
  const float* pc    = (const float*)d_in[0];
  const float* feats = (const float*)d_in[1];
  const int*   perm  = (const int*)d_in[2];
  float* out = (float*)d_out;

  // Gather domains: 524288 float4 + 32768 pts + 16384 rnds = 573440 -> 2240 blocks
  gather_kernel<<<2240, 256, 0, stream>>>(pc, feats, perm, out);

  // Largest chunk split whose partials fit in d_ws.
  // qblocks = 64, so nchunk=16 -> 1024 blocks (4/CU), nchunk=32 -> 2048 (8/CU).
  int nchunk = 1;
  if      (ws_size >= (size_t)BB * MM * 32 * sizeof(Partial)) nchunk = 32;  // 16.8 MB
  else if (ws_size >= (size_t)BB * MM * 16 * sizeof(Partial)) nchunk = 16;  //  8.4 MB
  else if (ws_size >= (size_t)BB * MM * 8  * sizeof(Partial)) nchunk = 8;
  else if (ws_size >= (size_t)BB * MM * 4  * sizeof(Partial)) nchunk = 4;
  else if (ws_size >= (size_t)BB * MM * 2  * sizeof(Partial)) nchunk = 2;

  int qblocks = BB * MM / QPB;   // 64
  if (nchunk > 1) {
    Partial* part = (Partial*)d_ws;
    knn_kernel<<<qblocks * nchunk, TPB, 0, stream>>>(pc, perm, part, out, nchunk);
    knn_merge_kernel<<<BB * MM / 256, 256, 0, stream>>>(part, out, nchunk);
  } else {
    knn_kernel<<<qblocks, TPB, 0, stream>>>(pc, perm, nullptr, out, 1);
  }
}